// Round 4
// baseline (911.237 us; speedup 1.0000x reference)
//
#include <hip/hip_runtime.h>

#define S_LEN 4096
#define D_MODEL 2048
#define FF_DIM 8192
#define QKV_LD 6144

typedef __attribute__((ext_vector_type(8))) short s16x8;
typedef __attribute__((ext_vector_type(4))) short s16x4;
typedef __attribute__((ext_vector_type(4))) float f32x4;
typedef __attribute__((ext_vector_type(16))) float f32x16;

__device__ __forceinline__ short f2bf(float f) {
  union { float f; unsigned u; } c; c.f = f;
  unsigned r = (c.u + 0x7fffu + ((c.u >> 16) & 1u)) >> 16;
  return (short)r;
}
__device__ __forceinline__ float bf2f(short s) {
  union { unsigned u; float f; } c; c.u = ((unsigned)(unsigned short)s) << 16;
  return c.f;
}

#define GLDS16(g, l) __builtin_amdgcn_global_load_lds( \
    (const __attribute__((address_space(1))) unsigned*)(g), \
    (__attribute__((address_space(3))) unsigned*)(l), 16, 0, 0)

template <int N> __device__ __forceinline__ void waitvm() {
  if constexpr (N == 0)      asm volatile("s_waitcnt vmcnt(0)" ::: "memory");
  else if constexpr (N == 3) asm volatile("s_waitcnt vmcnt(3)" ::: "memory");
  else if constexpr (N == 4) asm volatile("s_waitcnt vmcnt(4)" ::: "memory");
  else if constexpr (N == 6) asm volatile("s_waitcnt vmcnt(6)" ::: "memory");
  else                       asm volatile("s_waitcnt vmcnt(8)" ::: "memory");
}

// 2-bit XOR swizzle for 32x32 fragment reads: XOR row bits 3,4 (byte bits 9,10
// for 64B rows) into the 16B-quarter index (byte bits 4,5). Involution,
// row-preserving; spreads a 32-lane column read across all 32 banks.
__device__ __forceinline__ int swz(int byte_off) {
  return byte_off ^ (((byte_off >> 9) & 3) << 4);
}

// ---------------- fp32 -> bf16 bulk convert (n multiple of 8) ----------------
__global__ void conv_f32_bf16(const float* __restrict__ in, short* __restrict__ out, long n) {
  long i = ((long)blockIdx.x * blockDim.x + threadIdx.x) * 8;
  if (i >= n) return;
  f32x4 a = *(const f32x4*)(in + i);
  f32x4 b = *(const f32x4*)(in + i + 4);
  s16x8 o;
  o[0] = f2bf(a[0]); o[1] = f2bf(a[1]); o[2] = f2bf(a[2]); o[3] = f2bf(a[3]);
  o[4] = f2bf(b[0]); o[5] = f2bf(b[1]); o[6] = f2bf(b[2]); o[7] = f2bf(b[3]);
  *(s16x8*)(out + i) = o;
}

// ---------------- RMSNorm: fp32 [S,D=2048] -> bf16, block per row ----------------
__global__ void rmsnorm_kernel(const float* __restrict__ x, const float* __restrict__ w,
                               short* __restrict__ out) {
  const int row = blockIdx.x;
  const int t = threadIdx.x;
  const float* xr = x + (long)row * D_MODEL;
  f32x4 v0 = ((const f32x4*)xr)[t];
  f32x4 v1 = ((const f32x4*)xr)[256 + t];
  float ss = v0[0]*v0[0] + v0[1]*v0[1] + v0[2]*v0[2] + v0[3]*v0[3]
           + v1[0]*v1[0] + v1[1]*v1[1] + v1[2]*v1[2] + v1[3]*v1[3];
  #pragma unroll
  for (int o = 32; o > 0; o >>= 1) ss += __shfl_xor(ss, o, 64);
  __shared__ float red[4];
  if ((t & 63) == 0) red[t >> 6] = ss;
  __syncthreads();
  ss = red[0] + red[1] + red[2] + red[3];
  float scale = rsqrtf(ss * (1.0f / D_MODEL) + 1.1920929e-07f);
  f32x4 w0 = ((const f32x4*)w)[t];
  f32x4 w1 = ((const f32x4*)w)[256 + t];
  s16x4 o0, o1;
  #pragma unroll
  for (int i = 0; i < 4; i++) {
    o0[i] = f2bf(v0[i] * scale * w0[i]);
    o1[i] = f2bf(v1[i] * scale * w1[i]);
  }
  short* orow = out + (long)row * D_MODEL;
  ((s16x4*)orow)[t] = o0;
  ((s16x4*)orow)[256 + t] = o1;
}

// ---------------- RoPE in-place on q,k columns of qkv [S][6144], grid (S, 2) ----------------
__global__ void rope_kernel(short* __restrict__ qkv,
                            const float* __restrict__ cosb, const float* __restrict__ sinb) {
  const int s = blockIdx.x;
  short* row = qkv + (long)s * QKV_LD + (blockIdx.y ? D_MODEL : 0);
  const int j = threadIdx.x * 4;   // 0..1023
  f32x4 c = *(const f32x4*)(cosb + (long)s * (D_MODEL / 2) + j);
  f32x4 sn = *(const f32x4*)(sinb + (long)s * (D_MODEL / 2) + j);
  s16x4 x1 = *(s16x4*)(row + j);
  s16x4 x2 = *(s16x4*)(row + (D_MODEL / 2) + j);
  s16x4 o1, o2;
  #pragma unroll
  for (int i = 0; i < 4; i++) {
    float a = bf2f(x1[i]), b = bf2f(x2[i]);
    o1[i] = f2bf(a * c[i] - b * sn[i]);
    o2[i] = f2bf(a * sn[i] + b * c[i]);
  }
  *(s16x4*)(row + j) = o1;
  *(s16x4*)(row + (D_MODEL / 2) + j) = o2;
}

// ---------------- bf16 transpose [R][C] (row stride ld) -> [C][R], tile 32x32 ----------------
__global__ void transpose_kernel(const short* __restrict__ in, short* __restrict__ out,
                                 int R, int C, int ld) {
  __shared__ short tile[32][33];
  const int bx = blockIdx.x * 32, by = blockIdx.y * 32;
  const int x = threadIdx.x, y = threadIdx.y;
  #pragma unroll
  for (int i = 0; i < 32; i += 8) tile[y + i][x] = in[(long)(by + y + i) * ld + bx + x];
  __syncthreads();
  #pragma unroll
  for (int i = 0; i < 32; i += 8) out[(long)(bx + y + i) * R + by + x] = tile[x][y + i];
}

// ---------------- row softmax: fp32 [S,S] -> bf16 [S,S], block per row ----------------
__global__ void softmax_kernel(const float* __restrict__ sraw, short* __restrict__ pb) {
  const int row = blockIdx.x;
  const int t = threadIdx.x;
  const float* rp = sraw + (long)row * S_LEN;
  f32x4 v[4];
  #pragma unroll
  for (int i = 0; i < 4; i++) v[i] = ((const f32x4*)rp)[i * 256 + t];
  float m = -1e30f;
  #pragma unroll
  for (int i = 0; i < 4; i++)
    m = fmaxf(m, fmaxf(fmaxf(v[i][0], v[i][1]), fmaxf(v[i][2], v[i][3])));
  #pragma unroll
  for (int o = 32; o > 0; o >>= 1) m = fmaxf(m, __shfl_xor(m, o, 64));
  __shared__ float redm[4], reds[4];
  if ((t & 63) == 0) redm[t >> 6] = m;
  __syncthreads();
  m = fmaxf(fmaxf(redm[0], redm[1]), fmaxf(redm[2], redm[3]));
  float sum = 0.f;
  #pragma unroll
  for (int i = 0; i < 4; i++) {
    #pragma unroll
    for (int j = 0; j < 4; j++) { v[i][j] = __expf(v[i][j] - m); sum += v[i][j]; }
  }
  #pragma unroll
  for (int o = 32; o > 0; o >>= 1) sum += __shfl_xor(sum, o, 64);
  if ((t & 63) == 0) reds[t >> 6] = sum;
  __syncthreads();
  sum = reds[0] + reds[1] + reds[2] + reds[3];
  float inv = 1.0f / sum;
  short* prow = pb + (long)row * S_LEN;
  #pragma unroll
  for (int i = 0; i < 4; i++) {
    s16x4 o;
    #pragma unroll
    for (int j = 0; j < 4; j++) o[j] = f2bf(v[i][j] * inv);
    ((s16x4*)prow)[i * 256 + t] = o;
  }
}

// ============ Pipelined GEMM: BM=256 x BN tile, 8 waves, K32 4-slot ring ============
// 32x32x16 MFMA fragments; 2-bit XOR swizzle; counted vmcnt; XCD block swizzle.
// C[M,N] = A[M,K] x B[N,K]^T (bf16 in, strided lda/ldb/ldc).
// EPI: 0 bf16; 1 bf16 silu; 2 bf16 gmul*acc; 3 fp32 acc*scale; 4 fp32 res+acc.
template <int BN, int EPI>
__global__ __launch_bounds__(512)
void gemm_pipe(const short* __restrict__ A, const short* __restrict__ B,
               float* __restrict__ Cf, short* __restrict__ Cb,
               const short* __restrict__ gmul, const float* __restrict__ res,
               int K, int lda, int ldb, int ldc, float scale) {
  constexpr int BM = 256;
  constexpr int LPS = (BN == 256) ? 4 : 3;   // global_load_lds per thread per stage
  constexpr int WR = (BN == 256) ? 2 : 4;    // wave grid WR x WC
  constexpr int WC = 8 / WR;
  constexpr int TM = BM / WR / 32;           // 32x32 A tiles per wave (4 or 2)
  constexpr int TN = BN / WC / 32;           // 32x32 B tiles per wave (2)
  __shared__ short lds[4][(BM + BN) * 32];

  const int t = threadIdx.x;
  const int lane = t & 63, wid = t >> 6;
  const int wr = wid / WC, wc = wid % WC;
  const int l31 = lane & 31, lk = lane >> 5;   // row-in-tile, k-half

  // XCD-aware block swizzle (nwg always divisible by 8 here)
  const int nwg = gridDim.x * gridDim.y;
  int bid = blockIdx.y * gridDim.x + blockIdx.x;
  bid = (bid & 7) * (nwg >> 3) + (bid >> 3);
  const long m0 = (long)(bid / gridDim.x) * BM;
  const long n0 = (long)(bid % gridDim.x) * BN;

  // staging source offsets (inverse-swizzled global; LDS dest stays linear)
  const int ca0 = t, ca1 = t + 512;
  auto src_off = [&](int c, long r0, long ld) {
    int sb = swz(c * 16);
    return (r0 + (sb >> 6)) * ld + ((sb & 63) >> 1);
  };
  const long as0 = src_off(ca0, m0, lda);
  const long as1 = src_off(ca1, m0, lda);
  const long bs0 = src_off(ca0, n0, ldb);
  const long bs1 = (BN == 256) ? src_off(ca1, n0, ldb) : 0;

  f32x16 acc[TM][TN];
  #pragma unroll
  for (int m = 0; m < TM; m++)
    #pragma unroll
    for (int n = 0; n < TN; n++) acc[m][n] = (f32x16)(0.f);

  // fragment read offsets (swizzled, loop-invariant), in shorts
  // A tile tm, k-step ks: row = wr*(BM/WR)+tm*32+l31 ; byte col = ks*32 + lk*16
  int aoff[TM][2], boff[TN][2];
  #pragma unroll
  for (int m = 0; m < TM; m++)
    #pragma unroll
    for (int ks = 0; ks < 2; ks++) {
      int b = (wr * (BM / WR) + m * 32 + l31) * 64 + ks * 32 + lk * 16;
      aoff[m][ks] = swz(b) >> 1;
    }
  #pragma unroll
  for (int n = 0; n < TN; n++)
    #pragma unroll
    for (int ks = 0; ks < 2; ks++) {
      int b = (wc * (BN / WC) + n * 32 + l31) * 64 + ks * 32 + lk * 16;
      boff[n][ks] = swz(b) >> 1;
    }

  auto stage = [&](int ks) {
    short* la = (short*)lds[ks & 3];
    short* lb = la + BM * 32;
    const long kk = (long)ks * 32;
    GLDS16(A + as0 + kk, la + ca0 * 8);
    GLDS16(A + as1 + kk, la + ca1 * 8);
    GLDS16(B + bs0 + kk, lb + ca0 * 8);
    if constexpr (BN == 256) GLDS16(B + bs1 + kk, lb + ca1 * 8);
  };

  auto phase_compute = [&](int kt) {
    const short* la = (const short*)lds[kt & 3];
    const short* lb = la + BM * 32;
    s16x8 af[TM][2], bf[TN][2];
    #pragma unroll
    for (int m = 0; m < TM; m++) {
      af[m][0] = *(const s16x8*)(la + aoff[m][0]);
      af[m][1] = *(const s16x8*)(la + aoff[m][1]);
    }
    #pragma unroll
    for (int n = 0; n < TN; n++) {
      bf[n][0] = *(const s16x8*)(lb + boff[n][0]);
      bf[n][1] = *(const s16x8*)(lb + boff[n][1]);
    }
    __builtin_amdgcn_s_setprio(1);
    #pragma unroll
    for (int ks = 0; ks < 2; ks++)
      #pragma unroll
      for (int m = 0; m < TM; m++)
        #pragma unroll
        for (int n = 0; n < TN; n++)
          acc[m][n] = __builtin_amdgcn_mfma_f32_32x32x16_bf16(af[m][ks], bf[n][ks], acc[m][n], 0, 0, 0);
    __builtin_amdgcn_s_setprio(0);
  };

  const int NPH = K >> 5;   // K/32 >= 64 for all our shapes
  stage(0); stage(1); stage(2);
  waitvm<2 * LPS>();
  __builtin_amdgcn_s_barrier();
  for (int p = 0; p < NPH - 3; ++p) {
    stage(p + 3);                 // issue next tile first (hide HBM latency)
    phase_compute(p);
    waitvm<2 * LPS>();            // slot p+1 landed (counted, never 0)
    __builtin_amdgcn_s_barrier();
  }
  phase_compute(NPH - 3);
  waitvm<LPS>();
  __builtin_amdgcn_s_barrier();
  phase_compute(NPH - 2);
  waitvm<0>();
  __builtin_amdgcn_s_barrier();
  phase_compute(NPH - 1);

  // epilogue: 32x32 C/D layout: col = lane&31; row = (reg&3) + 8*(reg>>2) + 4*(lane>>5)
  #pragma unroll
  for (int m = 0; m < TM; m++) {
    #pragma unroll
    for (int n = 0; n < TN; n++) {
      const long col = n0 + wc * (BN / WC) + n * 32 + l31;
      const long rbase = m0 + wr * (BM / WR) + m * 32 + lk * 4;
      #pragma unroll
      for (int g = 0; g < 4; g++) {
        #pragma unroll
        for (int r = 0; r < 4; r++) {
          float v = acc[m][n][g * 4 + r];
          long idx = (rbase + g * 8 + r) * (long)ldc + col;
          if (EPI == 0) {
            Cb[idx] = f2bf(v);
          } else if (EPI == 1) {
            Cb[idx] = f2bf(v / (1.0f + __expf(-v)));
          } else if (EPI == 2) {
            Cb[idx] = f2bf(bf2f(gmul[idx]) * v);
          } else if (EPI == 3) {
            Cf[idx] = v * scale;
          } else {
            Cf[idx] = res[idx] + v;
          }
        }
      }
    }
  }
}

extern "C" void kernel_launch(void* const* d_in, const int* in_sizes, int n_in,
                              void* d_out, int out_size, void* d_ws, size_t ws_size,
                              hipStream_t stream) {
  const float* x      = (const float*)d_in[0];
  const float* w_rn1  = (const float*)d_in[1];
  const float* wq     = (const float*)d_in[2];
  const float* wk     = (const float*)d_in[3];
  const float* wv     = (const float*)d_in[4];
  const float* wo     = (const float*)d_in[5];
  const float* w_rn2  = (const float*)d_in[6];
  const float* w_gate = (const float*)d_in[7];
  const float* w_up   = (const float*)d_in[8];
  const float* w_down = (const float*)d_in[9];
  const float* cosb   = (const float*)d_in[10];
  const float* sinb   = (const float*)d_in[11];
  float* out = (float*)d_out;

  const long S = S_LEN, D = D_MODEL, FF = FF_DIM;
  char* ws = (char*)d_ws;
  size_t off = 0;
  auto alloc = [&](size_t bytes) { void* p = ws + off; off += (bytes + 255) & ~(size_t)255; return p; };

  short* qkv  = (short*)alloc(S * QKV_LD * 2);  // [S][q|k|v], ao overwrites v-cols later
  short* vT   = (short*)alloc(D * S * 2);       // v transposed [D][S]
  short* hb   = (short*)alloc(S * D * 2);       // rmsnorm out (reused for rms2)
  float* x1   = (float*)alloc(S * D * 4);       // residual-1 (fp32)
  short* wbuf = (short*)alloc(FF * D * 2);      // converted weight slot (max size)
  char*  u2   = (char*)alloc(S * S * 4);        // scores fp32, later SwiGLU bf16 [S,FF]
  float* sraw = (float*)u2;
  short* gbuf = (short*)u2;
  short* pb   = (short*)alloc(S * S * 2);       // probabilities bf16

  const float inv_scale = 1.0f / sqrtf((float)D_MODEL);
  const long DD = D * D, FD = FF * D;
  const int convDD = (int)(DD / 8 / 256), convFD = (int)(FD / 8 / 256);
  dim3 blk(256), blk5(512);
  dim3 gQKV(3 * D_MODEL / 256, S_LEN / 256);    // 24 x 16 = 384
  dim3 gS(S_LEN / 256, S_LEN / 256);            // 16 x 16 = 256
  dim3 gN2048(D_MODEL / 128, S_LEN / 256);      // 16 x 16 = 256 (BN=128)
  dim3 gF(FF_DIM / 256, S_LEN / 256);           // 32 x 16 = 512

  // 1. rms1
  rmsnorm_kernel<<<S_LEN, 256, 0, stream>>>(x, w_rn1, hb);
  // 2. fused QKV projection: wbuf = [wq; wk; wv] bf16, one GEMM N=6144
  conv_f32_bf16<<<convDD, blk, 0, stream>>>(wq, wbuf, DD);
  conv_f32_bf16<<<convDD, blk, 0, stream>>>(wk, wbuf + DD, DD);
  conv_f32_bf16<<<convDD, blk, 0, stream>>>(wv, wbuf + 2 * DD, DD);
  gemm_pipe<256, 0><<<gQKV, blk5, 0, stream>>>(hb, wbuf, nullptr, qkv, nullptr, nullptr,
                                               D_MODEL, D_MODEL, D_MODEL, QKV_LD, 1.f);
  // 3. RoPE on q, k (in place, strided)
  rope_kernel<<<dim3(S_LEN, 2), blk, 0, stream>>>(qkv, cosb, sinb);
  // 4. v -> vT
  transpose_kernel<<<dim3(D_MODEL / 32, S_LEN / 32), dim3(32, 8), 0, stream>>>(
      qkv + 2 * D_MODEL, vT, S_LEN, D_MODEL, QKV_LD);
  // 5. scores = q k^T / sqrt(D)  (fp32)
  gemm_pipe<256, 3><<<gS, blk5, 0, stream>>>(qkv, qkv + D_MODEL, sraw, nullptr, nullptr, nullptr,
                                             D_MODEL, QKV_LD, QKV_LD, S_LEN, inv_scale);
  // 6. softmax -> pb (bf16)
  softmax_kernel<<<S_LEN, 256, 0, stream>>>(sraw, pb);
  // 7. attn out = P @ V  -> into dead v-columns of qkv
  gemm_pipe<128, 0><<<gN2048, blk5, 0, stream>>>(pb, vT, nullptr, qkv + 2 * D_MODEL, nullptr, nullptr,
                                                 S_LEN, S_LEN, S_LEN, QKV_LD, 1.f);
  // 8. x1 = x + ao @ wo^T
  conv_f32_bf16<<<convDD, blk, 0, stream>>>(wo, wbuf, DD);
  gemm_pipe<128, 4><<<gN2048, blk5, 0, stream>>>(qkv + 2 * D_MODEL, wbuf, x1, nullptr, nullptr, x,
                                                 D_MODEL, QKV_LD, D_MODEL, D_MODEL, 1.f);
  // 9. rms2
  rmsnorm_kernel<<<S_LEN, 256, 0, stream>>>(x1, w_rn2, hb);
  // 10. gate = silu(h @ wg^T)
  conv_f32_bf16<<<convFD, blk, 0, stream>>>(w_gate, wbuf, FD);
  gemm_pipe<256, 1><<<gF, blk5, 0, stream>>>(hb, wbuf, nullptr, gbuf, nullptr, nullptr,
                                             D_MODEL, D_MODEL, D_MODEL, FF_DIM, 1.f);
  // 11. g = gate * (h @ wu^T)   (in place on gbuf)
  conv_f32_bf16<<<convFD, blk, 0, stream>>>(w_up, wbuf, FD);
  gemm_pipe<256, 2><<<gF, blk5, 0, stream>>>(hb, wbuf, nullptr, gbuf, gbuf, nullptr,
                                             D_MODEL, D_MODEL, D_MODEL, FF_DIM, 1.f);
  // 12. out = x1 + g @ wd^T
  conv_f32_bf16<<<convFD, blk, 0, stream>>>(w_down, wbuf, FD);
  gemm_pipe<128, 4><<<gN2048, blk5, 0, stream>>>(gbuf, wbuf, out, nullptr, nullptr, x1,
                                                 FF_DIM, FF_DIM, FF_DIM, D_MODEL, 1.f);
}

// Round 7
// 858.921 us; speedup vs baseline: 1.0609x; 1.0609x over previous
//
#include <hip/hip_runtime.h>

#define S_LEN 4096
#define D_MODEL 2048
#define FF_DIM 8192
#define QKV_LD 6144

typedef __attribute__((ext_vector_type(8))) short s16x8;
typedef __attribute__((ext_vector_type(4))) short s16x4;
typedef __attribute__((ext_vector_type(4))) float f32x4;

__device__ __forceinline__ short f2bf(float f) {
  union { float f; unsigned u; } c; c.f = f;
  unsigned r = (c.u + 0x7fffu + ((c.u >> 16) & 1u)) >> 16;
  return (short)r;
}
__device__ __forceinline__ float bf2f(short s) {
  union { unsigned u; float f; } c; c.u = ((unsigned)(unsigned short)s) << 16;
  return c.f;
}

#define GLDS16(g, l) __builtin_amdgcn_global_load_lds( \
    (const __attribute__((address_space(1))) unsigned*)(g), \
    (__attribute__((address_space(3))) unsigned*)(l), 16, 0, 0)

// XOR-swizzle for [rows][64 bf16] (128B rows): fold row bits 0-2 into the
// 16B-chunk index (byte bits 4-6). Involution; 16B-granularity preserved.
// Must be applied to the FULL byte offset (incl. k-subtile byte: ks*64 for
// 16x16x32 fragments — NOT ks*32, that was r5/r6's bug) — XOR on bits 4-6
// does not commute with adding 32B/64B.
__device__ __forceinline__ int swz(int b) {
  return b ^ (((b >> 7) & 7) << 4);
}

#define BAR()   __builtin_amdgcn_s_barrier()
#define LGKM0() asm volatile("s_waitcnt lgkmcnt(0)" ::: "memory")
#define VMC(n)  asm volatile("s_waitcnt vmcnt(" #n ")" ::: "memory")

// ---------------- fp32 -> bf16 bulk convert (n multiple of 8) ----------------
__global__ void conv_f32_bf16(const float* __restrict__ in, short* __restrict__ out, long n) {
  long i = ((long)blockIdx.x * blockDim.x + threadIdx.x) * 8;
  if (i >= n) return;
  f32x4 a = *(const f32x4*)(in + i);
  f32x4 b = *(const f32x4*)(in + i + 4);
  s16x8 o;
  o[0] = f2bf(a[0]); o[1] = f2bf(a[1]); o[2] = f2bf(a[2]); o[3] = f2bf(a[3]);
  o[4] = f2bf(b[0]); o[5] = f2bf(b[1]); o[6] = f2bf(b[2]); o[7] = f2bf(b[3]);
  *(s16x8*)(out + i) = o;
}

// ---------------- RMSNorm: fp32 [S,D=2048] -> bf16, block per row ----------------
__global__ void rmsnorm_kernel(const float* __restrict__ x, const float* __restrict__ w,
                               short* __restrict__ out) {
  const int row = blockIdx.x;
  const int t = threadIdx.x;
  const float* xr = x + (long)row * D_MODEL;
  f32x4 v0 = ((const f32x4*)xr)[t];
  f32x4 v1 = ((const f32x4*)xr)[256 + t];
  float ss = v0[0]*v0[0] + v0[1]*v0[1] + v0[2]*v0[2] + v0[3]*v0[3]
           + v1[0]*v1[0] + v1[1]*v1[1] + v1[2]*v1[2] + v1[3]*v1[3];
  #pragma unroll
  for (int o = 32; o > 0; o >>= 1) ss += __shfl_xor(ss, o, 64);
  __shared__ float red[4];
  if ((t & 63) == 0) red[t >> 6] = ss;
  __syncthreads();
  ss = red[0] + red[1] + red[2] + red[3];
  float scale = rsqrtf(ss * (1.0f / D_MODEL) + 1.1920929e-07f);
  f32x4 w0 = ((const f32x4*)w)[t];
  f32x4 w1 = ((const f32x4*)w)[256 + t];
  s16x4 o0, o1;
  #pragma unroll
  for (int i = 0; i < 4; i++) {
    o0[i] = f2bf(v0[i] * scale * w0[i]);
    o1[i] = f2bf(v1[i] * scale * w1[i]);
  }
  short* orow = out + (long)row * D_MODEL;
  ((s16x4*)orow)[t] = o0;
  ((s16x4*)orow)[256 + t] = o1;
}

// ---------------- RoPE in-place on q,k columns of qkv [S][6144], grid (S, 2) ----------------
__global__ void rope_kernel(short* __restrict__ qkv,
                            const float* __restrict__ cosb, const float* __restrict__ sinb) {
  const int s = blockIdx.x;
  short* row = qkv + (long)s * QKV_LD + (blockIdx.y ? D_MODEL : 0);
  const int j = threadIdx.x * 4;   // 0..1023
  f32x4 c = *(const f32x4*)(cosb + (long)s * (D_MODEL / 2) + j);
  f32x4 sn = *(const f32x4*)(sinb + (long)s * (D_MODEL / 2) + j);
  s16x4 x1 = *(s16x4*)(row + j);
  s16x4 x2 = *(s16x4*)(row + (D_MODEL / 2) + j);
  s16x4 o1, o2;
  #pragma unroll
  for (int i = 0; i < 4; i++) {
    float a = bf2f(x1[i]), b = bf2f(x2[i]);
    o1[i] = f2bf(a * c[i] - b * sn[i]);
    o2[i] = f2bf(a * sn[i] + b * c[i]);
  }
  *(s16x4*)(row + j) = o1;
  *(s16x4*)(row + (D_MODEL / 2) + j) = o2;
}

// ---------------- bf16 transpose [R][C] (row stride ld) -> [C][R], tile 32x32 ----------------
__global__ void transpose_kernel(const short* __restrict__ in, short* __restrict__ out,
                                 int R, int C, int ld) {
  __shared__ short tile[32][33];
  const int bx = blockIdx.x * 32, by = blockIdx.y * 32;
  const int x = threadIdx.x, y = threadIdx.y;
  #pragma unroll
  for (int i = 0; i < 32; i += 8) tile[y + i][x] = in[(long)(by + y + i) * ld + bx + x];
  __syncthreads();
  #pragma unroll
  for (int i = 0; i < 32; i += 8) out[(long)(bx + y + i) * R + by + x] = tile[x][y + i];
}

// ---------------- row softmax: fp32 [S,S] -> bf16 [S,S], block per row ----------------
__global__ void softmax_kernel(const float* __restrict__ sraw, short* __restrict__ pb) {
  const int row = blockIdx.x;
  const int t = threadIdx.x;
  const float* rp = sraw + (long)row * S_LEN;
  f32x4 v[4];
  #pragma unroll
  for (int i = 0; i < 4; i++) v[i] = ((const f32x4*)rp)[i * 256 + t];
  float m = -1e30f;
  #pragma unroll
  for (int i = 0; i < 4; i++)
    m = fmaxf(m, fmaxf(fmaxf(v[i][0], v[i][1]), fmaxf(v[i][2], v[i][3])));
  #pragma unroll
  for (int o = 32; o > 0; o >>= 1) m = fmaxf(m, __shfl_xor(m, o, 64));
  __shared__ float redm[4], reds[4];
  if ((t & 63) == 0) redm[t >> 6] = m;
  __syncthreads();
  m = fmaxf(fmaxf(redm[0], redm[1]), fmaxf(redm[2], redm[3]));
  float sum = 0.f;
  #pragma unroll
  for (int i = 0; i < 4; i++) {
    #pragma unroll
    for (int j = 0; j < 4; j++) { v[i][j] = __expf(v[i][j] - m); sum += v[i][j]; }
  }
  #pragma unroll
  for (int o = 32; o > 0; o >>= 1) sum += __shfl_xor(sum, o, 64);
  if ((t & 63) == 0) reds[t >> 6] = sum;
  __syncthreads();
  sum = reds[0] + reds[1] + reds[2] + reds[3];
  float inv = 1.0f / sum;
  short* prow = pb + (long)row * S_LEN;
  #pragma unroll
  for (int i = 0; i < 4; i++) {
    s16x4 o;
    #pragma unroll
    for (int j = 0; j < 4; j++) o[j] = f2bf(v[i][j] * inv);
    ((s16x4*)prow)[i * 256 + t] = o;
  }
}

// ---------------- shared epilogue ----------------
template <int EPI>
__device__ __forceinline__ void epi_store(float v, long idx, float* Cf, short* Cb,
                                          const short* gmul, const float* res, float scale) {
  if (EPI == 0)      Cb[idx] = f2bf(v);
  else if (EPI == 1) Cb[idx] = f2bf(v / (1.0f + __expf(-v)));
  else if (EPI == 2) Cb[idx] = f2bf(bf2f(gmul[idx]) * v);
  else if (EPI == 3) Cf[idx] = v * scale;
  else               Cf[idx] = res[idx] + v;
}

// ============ 8-phase GEMM, BM=256 BN=256 BK=64, 8 waves (2Mx4N), LDS dbuf ============
// C[M,N] = A[M,K] x B[N,K]^T. Per-wave C = 128x64. Phases: quadrant (mh,nh) of
// per-wave C x K=64. Counted vmcnt(4) at phases 4/8 only. lds[buf]: A 256x64 | B 256x64.
template <int EPI>
__global__ __launch_bounds__(512)
void gemm8p_n256(const short* __restrict__ A, const short* __restrict__ B,
                 float* __restrict__ Cf, short* __restrict__ Cb,
                 const short* __restrict__ gmul, const float* __restrict__ res,
                 int K, int lda, int ldb, int ldc, float scale) {
  __shared__ short lds[2][32768];   // 2 x 64KB
  const int t = threadIdx.x;
  const int lane = t & 63, wid = t >> 6;
  const int wr = wid >> 2, wc = wid & 3;       // 2 x 4 waves
  const int llo = lane & 15, lhi = lane >> 4;

  const int nwg = gridDim.x * gridDim.y;
  int bid = blockIdx.y * gridDim.x + blockIdx.x;
  bid = (bid & 7) * (nwg >> 3) + (bid >> 3);
  const long m0 = (long)(bid / gridDim.x) * 256;
  const long n0 = (long)(bid % gridDim.x) * 256;

  // staging geometry: chunk c covers LDS bytes [c*16,+16); source pre-swizzled
  const int c0 = t, c1 = t + 512;
  const int sb0 = swz(c0 * 16), sb1 = swz(c1 * 16);
  const short* srcA0 = A + (m0 + (sb0 >> 7)) * (long)lda + ((sb0 & 127) >> 1);
  const short* srcA1 = A + (m0 + (sb1 >> 7)) * (long)lda + ((sb1 & 127) >> 1);
  const short* srcB0 = B + (n0 + (sb0 >> 7)) * (long)ldb + ((sb0 & 127) >> 1);
  const short* srcB1 = B + (n0 + (sb1 >> 7)) * (long)ldb + ((sb1 & 127) >> 1);
  const long dA = 128L * lda, dB = 128L * ldb;
  const int NT = K >> 6, NI = NT >> 1;

  // fragment read offsets (shorts), ks folded INSIDE the swizzle.
  // 16x16x32 fragment: lane holds k = lhi*8 + [0,8) of subtile ks -> byte
  // offset row*128 + ks*64 + lhi*16.  Safe additive deltas (commute with swz):
  // MH*4096 shorts (64 rows), NH*2048 shorts (32 rows).
  int aof[4][2], bof[2][2];
  #pragma unroll
  for (int mf = 0; mf < 4; mf++)
    #pragma unroll
    for (int ks = 0; ks < 2; ks++)
      aof[mf][ks] = swz((wr * 128 + mf * 16 + llo) * 128 + ks * 64 + lhi * 16) >> 1;
  #pragma unroll
  for (int nf = 0; nf < 2; nf++)
    #pragma unroll
    for (int ks = 0; ks < 2; ks++)
      bof[nf][ks] = swz(32768 + (wc * 64 + nf * 16 + llo) * 128 + ks * 64 + lhi * 16) >> 1;

  f32x4 acc[8][4];
  #pragma unroll
  for (int m = 0; m < 8; m++)
    #pragma unroll
    for (int n = 0; n < 4; n++) acc[m][n] = (f32x4)(0.f);

  s16x8 ar[4][2], b0r[2][2], b1r[2][2];

  // p: 0=A rows[0,128) 1=A rows[128,256) 2=B rows[0,128) 3=B rows[128,256)
  auto stage = [&](int tt, int p) {
    if (tt >= NT) return;
    short* dst = (short*)lds[tt & 1] + p * 8192;
    const long kk = (long)tt * 64;
    const short *s0, *s1;
    if (p == 0)      { s0 = srcA0;      s1 = srcA1; }
    else if (p == 1) { s0 = srcA0 + dA; s1 = srcA1 + dA; }
    else if (p == 2) { s0 = srcB0;      s1 = srcB1; }
    else             { s0 = srcB0 + dB; s1 = srcB1 + dB; }
    GLDS16(s0 + kk, dst + c0 * 8);
    GLDS16(s1 + kk, dst + c1 * 8);
  };

#define LDA6(BUF, MH) { const short* lp = (const short*)lds[BUF]; \
  _Pragma("unroll") for (int mf = 0; mf < 4; mf++) \
  _Pragma("unroll") for (int ks = 0; ks < 2; ks++) \
    ar[mf][ks] = *(const s16x8*)(lp + aof[mf][ks] + (MH) * 4096); }
#define LDB6(BUF, NH, DST) { const short* lp = (const short*)lds[BUF]; \
  _Pragma("unroll") for (int nf = 0; nf < 2; nf++) \
  _Pragma("unroll") for (int ks = 0; ks < 2; ks++) \
    DST[nf][ks] = *(const s16x8*)(lp + bof[nf][ks] + (NH) * 2048); }
#define MFMAQ6(MH, NH, BR) { __builtin_amdgcn_s_setprio(1); \
  _Pragma("unroll") for (int ks = 0; ks < 2; ks++) \
  _Pragma("unroll") for (int mf = 0; mf < 4; mf++) \
  _Pragma("unroll") for (int nf = 0; nf < 2; nf++) \
    acc[(MH)*4+mf][(NH)*2+nf] = __builtin_amdgcn_mfma_f32_16x16x32_bf16( \
        ar[mf][ks], BR[nf][ks], acc[(MH)*4+mf][(NH)*2+nf], 0, 0, 0); \
  __builtin_amdgcn_s_setprio(0); }

  // prologue: A0, B0, B1 (A1 staged in P1/P2)
  stage(0, 0); stage(0, 1); stage(0, 2); stage(0, 3);
  stage(1, 2); stage(1, 3);
  VMC(4); BAR();

  for (int it = 0; it < NI; ++it) {
    const int tt = it * 2;
    const bool last = (it == NI - 1);
    // P1
    LDA6(0, 0); LDB6(0, 0, b0r); stage(tt + 1, 0);
    BAR(); LGKM0(); MFMAQ6(0, 0, b0r); BAR();
    // P2
    LDB6(0, 1, b1r); stage(tt + 1, 1);
    BAR(); LGKM0(); MFMAQ6(0, 1, b1r); BAR();
    // P3
    LDA6(0, 1); stage(tt + 2, 2);
    BAR(); LGKM0(); MFMAQ6(1, 1, b1r); BAR();
    // P4 (no ds_read; b0r still live)
    stage(tt + 2, 3);
    if (last) { VMC(0); } else { VMC(4); }
    BAR(); MFMAQ6(1, 0, b0r); BAR();
    // P5
    LDA6(1, 0); LDB6(1, 0, b0r); stage(tt + 2, 0);
    BAR(); LGKM0(); MFMAQ6(0, 0, b0r); BAR();
    // P6
    LDB6(1, 1, b1r); stage(tt + 2, 1);
    BAR(); LGKM0(); MFMAQ6(0, 1, b1r); BAR();
    // P7
    LDA6(1, 1); stage(tt + 3, 2);
    BAR(); LGKM0(); MFMAQ6(1, 1, b1r); BAR();
    // P8
    stage(tt + 3, 3);
    if (last) { VMC(0); } else { VMC(4); }
    BAR(); MFMAQ6(1, 0, b0r); BAR();
  }

  #pragma unroll
  for (int mf = 0; mf < 8; mf++) {
    const long row0 = m0 + wr * 128 + mf * 16 + lhi * 4;
    #pragma unroll
    for (int j = 0; j < 4; j++) {
      const long col = n0 + wc * 64 + (j >> 1) * 32 + (j & 1) * 16 + llo;
      #pragma unroll
      for (int r = 0; r < 4; r++)
        epi_store<EPI>(acc[mf][j][r], (row0 + r) * (long)ldc + col, Cf, Cb, gmul, res, scale);
    }
  }
#undef LDA6
#undef LDB6
#undef MFMAQ6
}

// ============ 8-phase GEMM, BM=256 BN=128 BK=64, 8 waves (4Mx2N), LDS ring-3 ============
// Per-wave C = 64x64. 2 phases per K-tile (nh halves). vmcnt(6) per tile.
template <int EPI>
__global__ __launch_bounds__(512)
void gemm8p_n128(const short* __restrict__ A, const short* __restrict__ B,
                 float* __restrict__ Cf, short* __restrict__ Cb,
                 const short* __restrict__ gmul, const float* __restrict__ res,
                 int K, int lda, int ldb, int ldc, float scale) {
  __shared__ short lds[3][24576];   // 3 x 48KB (A 256x64 | B 128x64)
  const int t = threadIdx.x;
  const int lane = t & 63, wid = t >> 6;
  const int wr = wid >> 1, wc = wid & 1;       // 4 x 2 waves
  const int llo = lane & 15, lhi = lane >> 4;

  const int nwg = gridDim.x * gridDim.y;
  int bid = blockIdx.y * gridDim.x + blockIdx.x;
  bid = (bid & 7) * (nwg >> 3) + (bid >> 3);
  const long m0 = (long)(bid / gridDim.x) * 256;
  const long n0 = (long)(bid % gridDim.x) * 128;

  const int c0 = t, c1 = t + 512;
  const int sb0 = swz(c0 * 16), sb1 = swz(c1 * 16);
  const short* srcA0 = A + (m0 + (sb0 >> 7)) * (long)lda + ((sb0 & 127) >> 1);
  const short* srcA1 = A + (m0 + (sb1 >> 7)) * (long)lda + ((sb1 & 127) >> 1);
  const short* srcB0 = B + (n0 + (sb0 >> 7)) * (long)ldb + ((sb0 & 127) >> 1);
  const short* srcB1 = B + (n0 + (sb1 >> 7)) * (long)ldb + ((sb1 & 127) >> 1);
  const long dA = 128L * lda;
  const int NT = K >> 6;

  int aof[4][2], bof[2][2];
  #pragma unroll
  for (int mf = 0; mf < 4; mf++)
    #pragma unroll
    for (int ks = 0; ks < 2; ks++)
      aof[mf][ks] = swz((wr * 64 + mf * 16 + llo) * 128 + ks * 64 + lhi * 16) >> 1;
  #pragma unroll
  for (int nf = 0; nf < 2; nf++)
    #pragma unroll
    for (int ks = 0; ks < 2; ks++)
      bof[nf][ks] = swz(32768 + (wc * 64 + nf * 16 + llo) * 128 + ks * 64 + lhi * 16) >> 1;

  f32x4 acc[4][4];
  #pragma unroll
  for (int m = 0; m < 4; m++)
    #pragma unroll
    for (int n = 0; n < 4; n++) acc[m][n] = (f32x4)(0.f);

  s16x8 ar[4][2], br[2][2];

  // p: 0=A rows[0,128) 1=A rows[128,256) 2=B rows[0,128)
  auto stage = [&](int tt, int slot, int p) {
    if (tt >= NT) return;
    short* dst = (short*)lds[slot] + p * 8192;
    const long kk = (long)tt * 64;
    const short *s0, *s1;
    if (p == 0)      { s0 = srcA0;      s1 = srcA1; }
    else if (p == 1) { s0 = srcA0 + dA; s1 = srcA1 + dA; }
    else             { s0 = srcB0;      s1 = srcB1; }
    GLDS16(s0 + kk, dst + c0 * 8);
    GLDS16(s1 + kk, dst + c1 * 8);
  };

#define LDA3(CUR) { const short* lp = (const short*)lds[CUR]; \
  _Pragma("unroll") for (int mf = 0; mf < 4; mf++) \
  _Pragma("unroll") for (int ks = 0; ks < 2; ks++) \
    ar[mf][ks] = *(const s16x8*)(lp + aof[mf][ks]); }
#define LDB3(CUR, NH) { const short* lp = (const short*)lds[CUR]; \
  _Pragma("unroll") for (int nf = 0; nf < 2; nf++) \
  _Pragma("unroll") for (int ks = 0; ks < 2; ks++) \
    br[nf][ks] = *(const s16x8*)(lp + bof[nf][ks] + (NH) * 2048); }
#define MFMAQ3(NH) { __builtin_amdgcn_s_setprio(1); \
  _Pragma("unroll") for (int ks = 0; ks < 2; ks++) \
  _Pragma("unroll") for (int mf = 0; mf < 4; mf++) \
  _Pragma("unroll") for (int nf = 0; nf < 2; nf++) \
    acc[mf][(NH)*2+nf] = __builtin_amdgcn_mfma_f32_16x16x32_bf16( \
        ar[mf][ks], br[nf][ks], acc[mf][(NH)*2+nf], 0, 0, 0); \
  __builtin_amdgcn_s_setprio(0); }

  // prologue: tiles 0 and 1 fully
  stage(0, 0, 0); stage(0, 0, 1); stage(0, 0, 2);
  stage(1, 1, 0); stage(1, 1, 1); stage(1, 1, 2);
  VMC(6); BAR();

  int cur = 0;
  for (int tt = 0; tt < NT; ++tt) {
    const int s2 = (cur >= 1) ? cur - 1 : 2;   // (cur+2)%3
    // P1: A + B(nh0) reads; stage A(t+2)
    LDA3(cur); LDB3(cur, 0); stage(tt + 2, s2, 0); stage(tt + 2, s2, 1);
    BAR(); LGKM0(); MFMAQ3(0); BAR();
    // P2: B(nh1) reads; stage B(t+2); counted vmcnt
    LDB3(cur, 1); stage(tt + 2, s2, 2);
    if (tt >= NT - 2) { VMC(0); } else { VMC(6); }
    BAR(); LGKM0(); MFMAQ3(1); BAR();
    cur = (cur == 2) ? 0 : cur + 1;
  }

  #pragma unroll
  for (int mf = 0; mf < 4; mf++) {
    const long row0 = m0 + wr * 64 + mf * 16 + lhi * 4;
    #pragma unroll
    for (int j = 0; j < 4; j++) {
      const long col = n0 + wc * 64 + (j >> 1) * 32 + (j & 1) * 16 + llo;
      #pragma unroll
      for (int r = 0; r < 4; r++)
        epi_store<EPI>(acc[mf][j][r], (row0 + r) * (long)ldc + col, Cf, Cb, gmul, res, scale);
    }
  }
#undef LDA3
#undef LDB3
#undef MFMAQ3
}

extern "C" void kernel_launch(void* const* d_in, const int* in_sizes, int n_in,
                              void* d_out, int out_size, void* d_ws, size_t ws_size,
                              hipStream_t stream) {
  const float* x      = (const float*)d_in[0];
  const float* w_rn1  = (const float*)d_in[1];
  const float* wq     = (const float*)d_in[2];
  const float* wk     = (const float*)d_in[3];
  const float* wv     = (const float*)d_in[4];
  const float* wo     = (const float*)d_in[5];
  const float* w_rn2  = (const float*)d_in[6];
  const float* w_gate = (const float*)d_in[7];
  const float* w_up   = (const float*)d_in[8];
  const float* w_down = (const float*)d_in[9];
  const float* cosb   = (const float*)d_in[10];
  const float* sinb   = (const float*)d_in[11];
  float* out = (float*)d_out;

  const long S = S_LEN, D = D_MODEL, FF = FF_DIM;
  char* ws = (char*)d_ws;
  size_t off = 0;
  auto alloc = [&](size_t bytes) { void* p = ws + off; off += (bytes + 255) & ~(size_t)255; return p; };

  short* qkv  = (short*)alloc(S * QKV_LD * 2);  // [S][q|k|v], ao overwrites v-cols later
  short* vT   = (short*)alloc(D * S * 2);       // v transposed [D][S]
  short* hb   = (short*)alloc(S * D * 2);       // rmsnorm out (reused for rms2)
  float* x1   = (float*)alloc(S * D * 4);       // residual-1 (fp32)
  short* wbuf = (short*)alloc(FF * D * 2);      // converted weight slot (max size)
  char*  u2   = (char*)alloc(S * S * 4);        // scores fp32, later SwiGLU bf16 [S,FF]
  float* sraw = (float*)u2;
  short* gbuf = (short*)u2;
  short* pb   = (short*)alloc(S * S * 2);       // probabilities bf16

  const float inv_scale = 1.0f / sqrtf((float)D_MODEL);
  const long DD = D * D, FD = FF * D;
  const int convDD = (int)(DD / 8 / 256), convFD = (int)(FD / 8 / 256);
  dim3 blk(256), blk5(512);
  dim3 gQKV(3 * D_MODEL / 256, S_LEN / 256);    // 24 x 16 = 384
  dim3 gS(S_LEN / 256, S_LEN / 256);            // 16 x 16 = 256
  dim3 gN2048(D_MODEL / 128, S_LEN / 256);      // 16 x 16 = 256 (BN=128)
  dim3 gF(FF_DIM / 256, S_LEN / 256);           // 32 x 16 = 512

  // 1. rms1
  rmsnorm_kernel<<<S_LEN, 256, 0, stream>>>(x, w_rn1, hb);
  // 2. fused QKV projection: wbuf = [wq; wk; wv] bf16, one GEMM N=6144
  conv_f32_bf16<<<convDD, blk, 0, stream>>>(wq, wbuf, DD);
  conv_f32_bf16<<<convDD, blk, 0, stream>>>(wk, wbuf + DD, DD);
  conv_f32_bf16<<<convDD, blk, 0, stream>>>(wv, wbuf + 2 * DD, DD);
  gemm8p_n256<0><<<gQKV, blk5, 0, stream>>>(hb, wbuf, nullptr, qkv, nullptr, nullptr,
                                            D_MODEL, D_MODEL, D_MODEL, QKV_LD, 1.f);
  // 3. RoPE on q, k (in place, strided)
  rope_kernel<<<dim3(S_LEN, 2), blk, 0, stream>>>(qkv, cosb, sinb);
  // 4. v -> vT
  transpose_kernel<<<dim3(D_MODEL / 32, S_LEN / 32), dim3(32, 8), 0, stream>>>(
      qkv + 2 * D_MODEL, vT, S_LEN, D_MODEL, QKV_LD);
  // 5. scores = q k^T / sqrt(D)  (fp32)
  gemm8p_n256<3><<<gS, blk5, 0, stream>>>(qkv, qkv + D_MODEL, sraw, nullptr, nullptr, nullptr,
                                          D_MODEL, QKV_LD, QKV_LD, S_LEN, inv_scale);
  // 6. softmax -> pb (bf16)
  softmax_kernel<<<S_LEN, 256, 0, stream>>>(sraw, pb);
  // 7. attn out = P @ V  -> into dead v-columns of qkv
  gemm8p_n128<0><<<gN2048, blk5, 0, stream>>>(pb, vT, nullptr, qkv + 2 * D_MODEL, nullptr, nullptr,
                                              S_LEN, S_LEN, S_LEN, QKV_LD, 1.f);
  // 8. x1 = x + ao @ wo^T
  conv_f32_bf16<<<convDD, blk, 0, stream>>>(wo, wbuf, DD);
  gemm8p_n128<4><<<gN2048, blk5, 0, stream>>>(qkv + 2 * D_MODEL, wbuf, x1, nullptr, nullptr, x,
                                              D_MODEL, QKV_LD, D_MODEL, D_MODEL, 1.f);
  // 9. rms2
  rmsnorm_kernel<<<S_LEN, 256, 0, stream>>>(x1, w_rn2, hb);
  // 10. gate = silu(h @ wg^T)
  conv_f32_bf16<<<convFD, blk, 0, stream>>>(w_gate, wbuf, FD);
  gemm8p_n256<1><<<gF, blk5, 0, stream>>>(hb, wbuf, nullptr, gbuf, nullptr, nullptr,
                                          D_MODEL, D_MODEL, D_MODEL, FF_DIM, 1.f);
  // 11. g = gate * (h @ wu^T)   (in place on gbuf)
  conv_f32_bf16<<<convFD, blk, 0, stream>>>(w_up, wbuf, FD);
  gemm8p_n256<2><<<gF, blk5, 0, stream>>>(hb, wbuf, nullptr, gbuf, gbuf, nullptr,
                                          D_MODEL, D_MODEL, D_MODEL, FF_DIM, 1.f);
  // 12. out = x1 + g @ wd^T
  conv_f32_bf16<<<convFD, blk, 0, stream>>>(w_down, wbuf, FD);
  gemm8p_n128<4><<<gN2048, blk5, 0, stream>>>(gbuf, wbuf, out, nullptr, nullptr, x1,
                                              FF_DIM, FF_DIM, FF_DIM, D_MODEL, 1.f);
}